// Round 10
// baseline (112.872 us; speedup 1.0000x reference)
//
#include <hip/hip_runtime.h>
#include <hip/hip_bf16.h>

// MMD loss via single-plane fp16 MFMA Gram pass — LDS-free, barrier-free.
//   Inputs are 4 MB (L2/L3-resident): staging through LDS was pure overhead
//   (r9: MfmaUtil 14%, occupancy 28%, >10x per-block stall). Each wave now
//   loads MFMA fragments directly from global (16B/lane, L1/L2-hit) and
//   free-runs: no barriers, 4 independent acc chains, latency hidden by TLP.
//   d2 = sq_i + sq_j - 2 dot (sq exact f32);  kernels = u+u^2+u^4+u^8+u^16.
// 128^2 tile (4 waves = 2x2 of 64x64), mfma_f32_32x32x16_f16, K=256.
// T1 XCD swizzle keeps consecutive blocks' A-panels on one XCD's L2.

#define N_TOTAL 8192
#define B_HALF 4096
#define D_DIM 256
#define TILE 128
#define NTILE 64          // 8192/128
#define NTRI 2080         // 64*65/2

typedef float f32x16 __attribute__((ext_vector_type(16)));
typedef _Float16 f16x8 __attribute__((ext_vector_type(8)));

__device__ __forceinline__ const float* row_base(const float* src, const float* tgt, int r) {
    return (r < B_HALF) ? src + (size_t)r * D_DIM : tgt + (size_t)(r - B_HALF) * D_DIM;
}

// fused: fp16 convert + row sq (wave per row) + per-block column partials.
// 64 blocks x 128 rows.
__global__ __launch_bounds__(256) void prep_kernel(const float* __restrict__ src,
                                                   const float* __restrict__ tgt,
                                                   _Float16* __restrict__ a16,
                                                   float* __restrict__ sq,
                                                   float* __restrict__ colpart) {
    int tid = threadIdx.x, w = tid >> 6, lane = tid & 63;
    int r0 = blockIdx.x * 128;
    #pragma unroll 4
    for (int i = 0; i < 32; ++i) {
        int row = r0 + w * 32 + i;
        const float* rp = row_base(src, tgt, row);
        float4 v = ((const float4*)rp)[lane];
        _Float16 h[4] = {(_Float16)v.x, (_Float16)v.y, (_Float16)v.z, (_Float16)v.w};
        ((ushort4*)(a16 + (size_t)row * D_DIM))[lane] = *(ushort4*)h;
        float s = v.x*v.x + v.y*v.y + v.z*v.z + v.w*v.w;
        #pragma unroll
        for (int off = 32; off; off >>= 1) s += __shfl_down(s, off, 64);
        if (lane == 0) sq[row] = s;
    }
    // column partials: thread t sums column t over this block's 128 rows (L2-warm)
    float c = 0.f;
    for (int r = r0; r < r0 + 128; ++r)
        c += row_base(src, tgt, r)[tid];
    colpart[blockIdx.x * D_DIM + tid] = c;
}

__global__ __launch_bounds__(256) void bw_kernel(const float* __restrict__ sq,
                                                 const float* __restrict__ colpart,
                                                 float* __restrict__ negc,
                                                 double* __restrict__ accum) {
    __shared__ double red[256];
    int t = threadIdx.x;
    double s = 0.0;
    for (int i = t; i < N_TOTAL; i += 256) s += (double)sq[i];
    red[t] = s;
    __syncthreads();
    for (int off = 128; off; off >>= 1) {
        if (t < off) red[t] += red[t + off];
        __syncthreads();
    }
    double sumsq = red[0];
    __syncthreads();
    float c = 0.f;
    #pragma unroll
    for (int k = 0; k < 64; ++k) c += colpart[k * D_DIM + t];
    red[t] = (double)c * (double)c;
    __syncthreads();
    for (int off = 128; off; off >>= 1) {
        if (t < off) red[t] += red[t + off];
        __syncthreads();
    }
    if (t == 0) {
        double S1 = 2.0 * (double)N_TOTAL * sumsq - 2.0 * red[0];
        double nn = (double)N_TOTAL * (double)N_TOTAL - (double)N_TOTAL;
        double bw = S1 / nn / 4.0;    // KERNEL_MUL^(KERNEL_NUM//2) = 4
        negc[0] = (float)(-1.4426950408889634 / (16.0 * bw));
        accum[0] = 0.0;
    }
}

__global__ __launch_bounds__(256, 4) void mmd_main(const _Float16* __restrict__ a16,
                                                   const float* __restrict__ sq,
                                                   const float* __restrict__ negc,
                                                   double* __restrict__ accum) {
    __shared__ float wsum[4];

    // T1: XCD swizzle (2080 % 8 == 0 -> bijective), then triangle decode (jt >= it)
    int b  = blockIdx.x;
    int bs = (b & 7) * (NTRI / 8) + (b >> 3);
    int it = 0, cum = 0;
    while (cum + (NTILE - it) <= bs) { cum += NTILE - it; ++it; }
    int jt = it + (bs - cum);

    int tid = threadIdx.x, lane = tid & 63, wid = tid >> 6;
    int wrow = wid >> 1, wcol = wid & 1;      // 2x2 wave grid; per-wave 64x64
    int rowA = it * TILE, rowB = jt * TILE;
    int c32 = lane & 31, khalf = lane >> 5;

    // lane's fragment rows: A rows rowA+wrow*64+{0,32}+c32, B rows rowB+wcol*64+{0,32}+c32
    // fragment k-slice: lane reads 8 f16 at k = kap*16 + khalf*8
    const _Float16* A0 = a16 + (size_t)(rowA + wrow * 64 + c32) * D_DIM + khalf * 8;
    const _Float16* B0 = a16 + (size_t)(rowB + wcol * 64 + c32) * D_DIM + khalf * 8;

    f32x16 acc[2][2] = {};

    #pragma unroll 4
    for (int kap = 0; kap < 16; ++kap) {      // K = 256 in steps of 16
        f16x8 af[2], bf[2];
        af[0] = *(const f16x8*)(A0 + kap * 16);
        af[1] = *(const f16x8*)(A0 + 32 * D_DIM + kap * 16);
        bf[0] = *(const f16x8*)(B0 + kap * 16);
        bf[1] = *(const f16x8*)(B0 + 32 * D_DIM + kap * 16);
        #pragma unroll
        for (int mt = 0; mt < 2; ++mt)
            #pragma unroll
            for (int nt = 0; nt < 2; ++nt)
                acc[mt][nt] = __builtin_amdgcn_mfma_f32_32x32x16_f16(af[mt], bf[nt], acc[mt][nt], 0, 0, 0);
    }

    // fused epilogue: d2 -> 5-kernel sum. C/D: col=lane&31, row=(reg&3)+8*(reg>>2)+4*khalf
    float nc = *negc;
    float sjn[2];
    #pragma unroll
    for (int nt = 0; nt < 2; ++nt)
        sjn[nt] = sq[rowB + wcol * 64 + nt * 32 + c32];
    float tsum = 0.f;
    #pragma unroll
    for (int mt = 0; mt < 2; ++mt) {
        #pragma unroll
        for (int reg = 0; reg < 16; ++reg) {
            int i = rowA + wrow * 64 + mt * 32 + (reg & 3) + 8 * (reg >> 2) + 4 * khalf;
            float si = sq[i];
            #pragma unroll
            for (int nt = 0; nt < 2; ++nt) {
                float d2 = fmaxf(si + sjn[nt] - 2.0f * acc[mt][nt][reg], 0.f);
                float u  = exp2f(nc * d2);
                float u2 = u * u, u4 = u2 * u2, u8 = u4 * u4;
                tsum += u + u2 + u4 + u8 + u8 * u8;
            }
        }
    }
    float scale = (((it < 32) == (jt < 32)) ? 1.f : -1.f) * ((it == jt) ? 1.f : 2.f);
    tsum *= scale;

    #pragma unroll
    for (int off = 32; off; off >>= 1) tsum += __shfl_down(tsum, off, 64);
    if (lane == 0) wsum[wid] = tsum;
    __syncthreads();
    if (tid == 0) {
        float t = wsum[0] + wsum[1] + wsum[2] + wsum[3];
        atomicAdd(accum, (double)t);
    }
}

__global__ void finalize_kernel(const double* __restrict__ accum, float* __restrict__ out) {
    out[0] = (float)(accum[0] / ((double)B_HALF * (double)B_HALF));
}

extern "C" void kernel_launch(void* const* d_in, const int* in_sizes, int n_in,
                              void* d_out, int out_size, void* d_ws, size_t ws_size,
                              hipStream_t stream) {
    const float* src = (const float*)d_in[0];
    const float* tgt = (const float*)d_in[1];
    float* out = (float*)d_out;

    char* ws = (char*)d_ws;
    float*  sq      = (float*)ws;                         // 32 KB
    float*  colpart = (float*)(ws + 32768);               // 64 x 256 f32 = 64 KB
    float*  negc    = (float*)(ws + 98304);
    double* accum   = (double*)(ws + 98312);
    _Float16* a16   = (_Float16*)(ws + 131072);           // 4 MB plane

    prep_kernel<<<64, 256, 0, stream>>>(src, tgt, a16, sq, colpart);
    bw_kernel<<<1, 256, 0, stream>>>(sq, colpart, negc, accum);
    mmd_main<<<NTRI, 256, 0, stream>>>(a16, sq, negc, accum);
    finalize_kernel<<<1, 1, 0, stream>>>(accum, out);
}

// Round 11
// 79.111 us; speedup vs baseline: 1.4268x; 1.4268x over previous
//
#include <hip/hip_runtime.h>
#include <hip/hip_bf16.h>

// MMD loss via single-plane fp16 MFMA Gram pass — LDS-free, barrier-free,
// FRAGMENT-MAJOR layout. r10's direct-global loads were 512B-strided
// (16B/lane scattered over 64 cache lines -> latency-bound, MfmaUtil 8%).
// Fix: store the fp16 plane as a16f[kb][row][8] (k tiled by 8). A lane's
// MFMA fragment = 16B at ((kb*8192+row)*8); consecutive lanes (c32) read
// consecutive 16B -> each wave-load is two contiguous 512B segments.
//   d2 = sq_i + sq_j - 2 dot (sq exact f32);  kernels = u+u^2+u^4+u^8+u^16.
// 128^2 tile (4 waves = 2x2 of 64x64), mfma_f32_32x32x16_f16, K=256.
// T1 XCD swizzle for panel L2 locality.

#define N_TOTAL 8192
#define B_HALF 4096
#define D_DIM 256
#define TILE 128
#define NTILE 64          // 8192/128
#define NTRI 2080         // 64*65/2

typedef float f32x16 __attribute__((ext_vector_type(16)));
typedef _Float16 f16x8 __attribute__((ext_vector_type(8)));

__device__ __forceinline__ const float* row_base(const float* src, const float* tgt, int r) {
    return (r < B_HALF) ? src + (size_t)r * D_DIM : tgt + (size_t)(r - B_HALF) * D_DIM;
}

// fused: fp16 convert (fragment-major write) + row sq + per-block column partials.
// 64 blocks x 128 rows. Lane covers k = 4*lane .. 4*lane+3 of its row:
// kb = lane>>1, e0 = (lane&1)*4 -> 8B ushort4 store at ((kb*8192+row)*8+e0).
__global__ __launch_bounds__(256) void prep_kernel(const float* __restrict__ src,
                                                   const float* __restrict__ tgt,
                                                   _Float16* __restrict__ a16f,
                                                   float* __restrict__ sq,
                                                   float* __restrict__ colpart) {
    int tid = threadIdx.x, w = tid >> 6, lane = tid & 63;
    int r0 = blockIdx.x * 128;
    #pragma unroll 4
    for (int i = 0; i < 32; ++i) {
        int row = r0 + w * 32 + i;
        const float* rp = row_base(src, tgt, row);
        float4 v = ((const float4*)rp)[lane];
        _Float16 h[4] = {(_Float16)v.x, (_Float16)v.y, (_Float16)v.z, (_Float16)v.w};
        size_t idx = ((size_t)(lane >> 1) * N_TOTAL + row) * 8 + (lane & 1) * 4;
        *(ushort4*)(a16f + idx) = *(ushort4*)h;
        float s = v.x*v.x + v.y*v.y + v.z*v.z + v.w*v.w;
        #pragma unroll
        for (int off = 32; off; off >>= 1) s += __shfl_down(s, off, 64);
        if (lane == 0) sq[row] = s;
    }
    // column partials: thread t sums column t over this block's 128 rows (L2-warm)
    float c = 0.f;
    for (int r = r0; r < r0 + 128; ++r)
        c += row_base(src, tgt, r)[tid];
    colpart[blockIdx.x * D_DIM + tid] = c;
}

__global__ __launch_bounds__(256) void bw_kernel(const float* __restrict__ sq,
                                                 const float* __restrict__ colpart,
                                                 float* __restrict__ negc,
                                                 double* __restrict__ accum) {
    __shared__ double red[256];
    int t = threadIdx.x;
    double s = 0.0;
    for (int i = t; i < N_TOTAL; i += 256) s += (double)sq[i];
    red[t] = s;
    __syncthreads();
    for (int off = 128; off; off >>= 1) {
        if (t < off) red[t] += red[t + off];
        __syncthreads();
    }
    double sumsq = red[0];
    __syncthreads();
    float c = 0.f;
    #pragma unroll
    for (int k = 0; k < 64; ++k) c += colpart[k * D_DIM + t];
    red[t] = (double)c * (double)c;
    __syncthreads();
    for (int off = 128; off; off >>= 1) {
        if (t < off) red[t] += red[t + off];
        __syncthreads();
    }
    if (t == 0) {
        double S1 = 2.0 * (double)N_TOTAL * sumsq - 2.0 * red[0];
        double nn = (double)N_TOTAL * (double)N_TOTAL - (double)N_TOTAL;
        double bw = S1 / nn / 4.0;    // KERNEL_MUL^(KERNEL_NUM//2) = 4
        negc[0] = (float)(-1.4426950408889634 / (16.0 * bw));
        accum[0] = 0.0;
    }
}

__global__ __launch_bounds__(256, 4) void mmd_main(const _Float16* __restrict__ a16f,
                                                   const float* __restrict__ sq,
                                                   const float* __restrict__ negc,
                                                   double* __restrict__ accum) {
    __shared__ float wsum[4];

    // T1: XCD swizzle (2080 % 8 == 0 -> bijective), then triangle decode (jt >= it)
    int b  = blockIdx.x;
    int bs = (b & 7) * (NTRI / 8) + (b >> 3);
    int it = 0, cum = 0;
    while (cum + (NTILE - it) <= bs) { cum += NTILE - it; ++it; }
    int jt = it + (bs - cum);

    int tid = threadIdx.x, lane = tid & 63, wid = tid >> 6;
    int wrow = wid >> 1, wcol = wid & 1;      // 2x2 wave grid; per-wave 64x64
    int rowA = it * TILE, rowB = jt * TILE;
    int c32 = lane & 31, khalf = lane >> 5;

    // fragment-major: element (row, k) at a16f[((k>>3)*8192 + row)*8 + (k&7)].
    // lane fragment (kap, khalf): kb = kap*2 + khalf, 16B at ((kb*8192+row)*8).
    const _Float16* PA = a16f + (size_t)khalf * (N_TOTAL * 8)
                              + (size_t)(rowA + wrow * 64 + c32) * 8;
    const _Float16* PB = a16f + (size_t)khalf * (N_TOTAL * 8)
                              + (size_t)(rowB + wcol * 64 + c32) * 8;

    f32x16 acc[2][2] = {};

    #pragma unroll 4
    for (int kap = 0; kap < 16; ++kap) {      // K = 256 in steps of 16
        size_t ko = (size_t)kap * (N_TOTAL * 16);   // 2 k-blocks per step
        f16x8 af[2], bf[2];
        af[0] = *(const f16x8*)(PA + ko);
        af[1] = *(const f16x8*)(PA + ko + 32 * 8);
        bf[0] = *(const f16x8*)(PB + ko);
        bf[1] = *(const f16x8*)(PB + ko + 32 * 8);
        #pragma unroll
        for (int mt = 0; mt < 2; ++mt)
            #pragma unroll
            for (int nt = 0; nt < 2; ++nt)
                acc[mt][nt] = __builtin_amdgcn_mfma_f32_32x32x16_f16(af[mt], bf[nt], acc[mt][nt], 0, 0, 0);
    }

    // fused epilogue: d2 -> 5-kernel sum. C/D: col=lane&31, row=(reg&3)+8*(reg>>2)+4*khalf
    float nc = *negc;
    float sjn[2];
    #pragma unroll
    for (int nt = 0; nt < 2; ++nt)
        sjn[nt] = sq[rowB + wcol * 64 + nt * 32 + c32];
    float tsum = 0.f;
    #pragma unroll
    for (int mt = 0; mt < 2; ++mt) {
        #pragma unroll
        for (int reg = 0; reg < 16; ++reg) {
            int i = rowA + wrow * 64 + mt * 32 + (reg & 3) + 8 * (reg >> 2) + 4 * khalf;
            float si = sq[i];
            #pragma unroll
            for (int nt = 0; nt < 2; ++nt) {
                float d2 = fmaxf(si + sjn[nt] - 2.0f * acc[mt][nt][reg], 0.f);
                float u  = exp2f(nc * d2);
                float u2 = u * u, u4 = u2 * u2, u8 = u4 * u4;
                tsum += u + u2 + u4 + u8 + u8 * u8;
            }
        }
    }
    float scale = (((it < 32) == (jt < 32)) ? 1.f : -1.f) * ((it == jt) ? 1.f : 2.f);
    tsum *= scale;

    #pragma unroll
    for (int off = 32; off; off >>= 1) tsum += __shfl_down(tsum, off, 64);
    if (lane == 0) wsum[wid] = tsum;
    __syncthreads();
    if (tid == 0) {
        float t = wsum[0] + wsum[1] + wsum[2] + wsum[3];
        atomicAdd(accum, (double)t);
    }
}

__global__ void finalize_kernel(const double* __restrict__ accum, float* __restrict__ out) {
    out[0] = (float)(accum[0] / ((double)B_HALF * (double)B_HALF));
}

extern "C" void kernel_launch(void* const* d_in, const int* in_sizes, int n_in,
                              void* d_out, int out_size, void* d_ws, size_t ws_size,
                              hipStream_t stream) {
    const float* src = (const float*)d_in[0];
    const float* tgt = (const float*)d_in[1];
    float* out = (float*)d_out;

    char* ws = (char*)d_ws;
    float*  sq      = (float*)ws;                         // 32 KB
    float*  colpart = (float*)(ws + 32768);               // 64 x 256 f32 = 64 KB
    float*  negc    = (float*)(ws + 98304);
    double* accum   = (double*)(ws + 98312);
    _Float16* a16f  = (_Float16*)(ws + 131072);           // 4 MB plane (fragment-major)

    prep_kernel<<<64, 256, 0, stream>>>(src, tgt, a16f, sq, colpart);
    bw_kernel<<<1, 256, 0, stream>>>(sq, colpart, negc, accum);
    mmd_main<<<NTRI, 256, 0, stream>>>(a16f, sq, negc, accum);
    finalize_kernel<<<1, 1, 0, stream>>>(accum, out);
}

// Round 12
// 79.039 us; speedup vs baseline: 1.4280x; 1.0009x over previous
//
#include <hip/hip_runtime.h>
#include <hip/hip_bf16.h>

// MMD loss via single-plane fp16 MFMA Gram pass, fragment-major layout.
//   a16f[kb][row][8]: lane's MFMA fragment = 16B at ((kb*8192+row)*8);
//   consecutive lanes read consecutive 16B -> coalesced wave-loads.
//   d2 = sq_i + sq_j - 2 dot (sq exact f32);  kernels = u+u^2+u^4+u^8+u^16.
// mmd_main: A-panel staged ONCE in LDS (64 KB fragment-major, 1 barrier),
//   B direct from global; free-running waves, no per-chunk barriers.
// prep: coalesced fragment-major stores (scatter moved to the load side).
// 128^2 tile (4 waves = 2x2 of 64x64), mfma_f32_32x32x16_f16, K=256.
// T1 XCD swizzle (2080 % 8 == 0 -> bijective).

#define N_TOTAL 8192
#define B_HALF 4096
#define D_DIM 256
#define TILE 128
#define NTILE 64          // 8192/128
#define NTRI 2080         // 64*65/2

typedef float f32x16 __attribute__((ext_vector_type(16)));
typedef _Float16 f16x8 __attribute__((ext_vector_type(8)));

__device__ __forceinline__ const float* row_base(const float* src, const float* tgt, int r) {
    return (r < B_HALF) ? src + (size_t)r * D_DIM : tgt + (size_t)(r - B_HALF) * D_DIM;
}

// 256 blocks x 32 rows: sq + colpart (coalesced row reads), then
// fragment-major fp16 convert with COALESCED 16B stores.
__global__ __launch_bounds__(256) void prep_kernel(const float* __restrict__ src,
                                                   const float* __restrict__ tgt,
                                                   _Float16* __restrict__ a16f,
                                                   float* __restrict__ sq,
                                                   float* __restrict__ colpart) {
    int tid = threadIdx.x, w = tid >> 6, lane = tid & 63;
    int r0 = blockIdx.x * 32;

    // row sq: each wave handles 8 rows, lane = float4 slot
    #pragma unroll
    for (int i = 0; i < 8; ++i) {
        int row = r0 + w * 8 + i;
        const float* rp = row_base(src, tgt, row);
        float4 v = ((const float4*)rp)[lane];
        float s = v.x*v.x + v.y*v.y + v.z*v.z + v.w*v.w;
        #pragma unroll
        for (int off = 32; off; off >>= 1) s += __shfl_down(s, off, 64);
        if (lane == 0) sq[row] = s;
    }

    // column partials: thread t sums column t over this block's 32 rows
    float c = 0.f;
    for (int r = r0; r < r0 + 32; ++r)
        c += row_base(src, tgt, r)[tid];
    colpart[blockIdx.x * D_DIM + tid] = c;

    // fragment-major convert: wave-task = (kb, 64-row group).
    // 32 kb x 128 groups = 4096 tasks / 1024 waves = 4 per wave.
    // lane loads 8 floats from its row (strided), stores 16B coalesced.
    int wg = blockIdx.x * 4 + w;                   // 0..1023
    #pragma unroll
    for (int i = 0; i < 4; ++i) {
        int t  = wg * 4 + i;                       // 0..4095
        int kb = t >> 7, rg = t & 127;
        int row = rg * 64 + lane;
        const float* rp = row_base(src, tgt, row) + kb * 8;
        float4 v0 = ((const float4*)rp)[0];
        float4 v1 = ((const float4*)rp)[1];
        _Float16 h[8] = {(_Float16)v0.x, (_Float16)v0.y, (_Float16)v0.z, (_Float16)v0.w,
                         (_Float16)v1.x, (_Float16)v1.y, (_Float16)v1.z, (_Float16)v1.w};
        *(f16x8*)(a16f + ((size_t)kb * N_TOTAL + row) * 8) = *(f16x8*)h;
    }
}

__global__ __launch_bounds__(256) void bw_kernel(const float* __restrict__ sq,
                                                 const float* __restrict__ colpart,
                                                 float* __restrict__ negc,
                                                 double* __restrict__ accum) {
    __shared__ double red[256];
    int t = threadIdx.x;
    double s = 0.0;
    for (int i = t; i < N_TOTAL; i += 256) s += (double)sq[i];
    red[t] = s;
    __syncthreads();
    for (int off = 128; off; off >>= 1) {
        if (t < off) red[t] += red[t + off];
        __syncthreads();
    }
    double sumsq = red[0];
    __syncthreads();
    float c = 0.f;
    for (int k = 0; k < 256; ++k) c += colpart[k * D_DIM + t];
    red[t] = (double)c * (double)c;
    __syncthreads();
    for (int off = 128; off; off >>= 1) {
        if (t < off) red[t] += red[t + off];
        __syncthreads();
    }
    if (t == 0) {
        double S1 = 2.0 * (double)N_TOTAL * sumsq - 2.0 * red[0];
        double nn = (double)N_TOTAL * (double)N_TOTAL - (double)N_TOTAL;
        double bw = S1 / nn / 4.0;    // KERNEL_MUL^(KERNEL_NUM//2) = 4
        negc[0] = (float)(-1.4426950408889634 / (16.0 * bw));
        accum[0] = 0.0;
    }
}

__device__ __forceinline__ void gload_lds16(const void* g, void* l) {
    __builtin_amdgcn_global_load_lds((const __attribute__((address_space(1))) unsigned int*)g,
                                     (__attribute__((address_space(3))) unsigned int*)l,
                                     16, 0, 0);
}

__global__ __launch_bounds__(256, 2) void mmd_main(const _Float16* __restrict__ a16f,
                                                   const float* __restrict__ sq,
                                                   const float* __restrict__ negc,
                                                   double* __restrict__ accum) {
    __shared__ _Float16 Asm[32 * TILE * 8];   // 64 KB, fragment-major [kb][r][8]
    __shared__ float wsum[4];

    // T1: XCD swizzle (2080 % 8 == 0 -> bijective), then triangle decode (jt >= it)
    int b  = blockIdx.x;
    int bs = (b & 7) * (NTRI / 8) + (b >> 3);
    int it = 0, cum = 0;
    while (cum + (NTILE - it) <= bs) { cum += NTILE - it; ++it; }
    int jt = it + (bs - cum);

    int tid = threadIdx.x, lane = tid & 63, wid = tid >> 6;
    int wrow = wid >> 1, wcol = wid & 1;      // 2x2 wave grid; per-wave 64x64
    int rowA = it * TILE, rowB = jt * TILE;
    int c32 = lane & 31, khalf = lane >> 5;

    // stage A panel (64 KB = 4096 16B-chunks, 16 per thread), linear dest
    #pragma unroll
    for (int i = 0; i < 16; ++i) {
        int g0 = i * 256 + wid * 64;          // wave-uniform chunk base
        int g  = g0 + lane;
        int kb = g >> 7, r = g & 127;
        gload_lds16(a16f + ((size_t)kb * N_TOTAL + rowA + r) * 8,
                    Asm + (size_t)g0 * 8);
    }

    const _Float16* PB = a16f + (size_t)khalf * (N_TOTAL * 8)
                              + (size_t)(rowB + wcol * 64 + c32) * 8;

    asm volatile("s_waitcnt vmcnt(0)" ::: "memory");
    __syncthreads();                           // the ONLY staging barrier

    f32x16 acc[2][2] = {};

    #pragma unroll 4
    for (int kap = 0; kap < 16; ++kap) {      // K = 256 in steps of 16
        int kb = kap * 2 + khalf;
        size_t ko = (size_t)kap * (N_TOTAL * 16);
        f16x8 af[2], bf[2];
        af[0] = *(const f16x8*)&Asm[((size_t)kb * TILE + wrow * 64 + c32) * 8];
        af[1] = *(const f16x8*)&Asm[((size_t)kb * TILE + wrow * 64 + 32 + c32) * 8];
        bf[0] = *(const f16x8*)(PB + ko);
        bf[1] = *(const f16x8*)(PB + ko + 32 * 8);
        #pragma unroll
        for (int mt = 0; mt < 2; ++mt)
            #pragma unroll
            for (int nt = 0; nt < 2; ++nt)
                acc[mt][nt] = __builtin_amdgcn_mfma_f32_32x32x16_f16(af[mt], bf[nt], acc[mt][nt], 0, 0, 0);
    }

    // fused epilogue: d2 -> 5-kernel sum. C/D: col=lane&31, row=(reg&3)+8*(reg>>2)+4*khalf
    float nc = *negc;
    float sjn[2];
    #pragma unroll
    for (int nt = 0; nt < 2; ++nt)
        sjn[nt] = sq[rowB + wcol * 64 + nt * 32 + c32];
    float tsum = 0.f;
    #pragma unroll
    for (int mt = 0; mt < 2; ++mt) {
        #pragma unroll
        for (int reg = 0; reg < 16; ++reg) {
            int i = rowA + wrow * 64 + mt * 32 + (reg & 3) + 8 * (reg >> 2) + 4 * khalf;
            float si = sq[i];
            #pragma unroll
            for (int nt = 0; nt < 2; ++nt) {
                float d2 = fmaxf(si + sjn[nt] - 2.0f * acc[mt][nt][reg], 0.f);
                float u  = exp2f(nc * d2);
                float u2 = u * u, u4 = u2 * u2, u8 = u4 * u4;
                tsum += u + u2 + u4 + u8 + u8 * u8;
            }
        }
    }
    float scale = (((it < 32) == (jt < 32)) ? 1.f : -1.f) * ((it == jt) ? 1.f : 2.f);
    tsum *= scale;

    #pragma unroll
    for (int off = 32; off; off >>= 1) tsum += __shfl_down(tsum, off, 64);
    if (lane == 0) wsum[wid] = tsum;
    __syncthreads();
    if (tid == 0) {
        float t = wsum[0] + wsum[1] + wsum[2] + wsum[3];
        atomicAdd(accum, (double)t);
    }
}

__global__ void finalize_kernel(const double* __restrict__ accum, float* __restrict__ out) {
    out[0] = (float)(accum[0] / ((double)B_HALF * (double)B_HALF));
}

extern "C" void kernel_launch(void* const* d_in, const int* in_sizes, int n_in,
                              void* d_out, int out_size, void* d_ws, size_t ws_size,
                              hipStream_t stream) {
    const float* src = (const float*)d_in[0];
    const float* tgt = (const float*)d_in[1];
    float* out = (float*)d_out;

    char* ws = (char*)d_ws;
    float*  sq      = (float*)ws;                         // 32 KB
    float*  colpart = (float*)(ws + 32768);               // 256 x 256 f32 = 256 KB
    float*  negc    = (float*)(ws + 294912);
    double* accum   = (double*)(ws + 294920);
    _Float16* a16f  = (_Float16*)(ws + 327680);           // 4 MB plane (fragment-major)

    prep_kernel<<<256, 256, 0, stream>>>(src, tgt, a16f, sq, colpart);
    bw_kernel<<<1, 256, 0, stream>>>(sq, colpart, negc, accum);
    mmd_main<<<NTRI, 256, 0, stream>>>(a16f, sq, negc, accum);
    finalize_kernel<<<1, 1, 0, stream>>>(accum, out);
}

// Round 13
// 71.875 us; speedup vs baseline: 1.5704x; 1.0997x over previous
//
#include <hip/hip_runtime.h>
#include <hip/hip_bf16.h>

// MMD loss via single-plane fp16 MFMA Gram pass, fragment-major layout.
//   a16f[kb][row][8]: lane's MFMA fragment = 16B at ((kb*8192+row)*8);
//   consecutive lanes read consecutive 16B -> coalesced wave-loads.
//   d2 = sq_i + sq_j - 2 dot (sq exact f32);  kernels = u+u^2+u^4+u^8+u^16.
// mmd_main: r11's measured-good LDS-free kernel (direct global loads, no
//   barriers, free-running waves; A-LDS variant r12 was 52.6us @ 15% occ ->
//   reverted) + T5 setprio (free-running waves = attn-like regime, m191).
// prep: r12's measured-good coalesced fragment-major stores.
// 128^2 tile (4 waves = 2x2 of 64x64), mfma_f32_32x32x16_f16, K=256.
// T1 XCD swizzle (2080 % 8 == 0 -> bijective).

#define N_TOTAL 8192
#define B_HALF 4096
#define D_DIM 256
#define TILE 128
#define NTILE 64          // 8192/128
#define NTRI 2080         // 64*65/2

typedef float f32x16 __attribute__((ext_vector_type(16)));
typedef _Float16 f16x8 __attribute__((ext_vector_type(8)));

__device__ __forceinline__ const float* row_base(const float* src, const float* tgt, int r) {
    return (r < B_HALF) ? src + (size_t)r * D_DIM : tgt + (size_t)(r - B_HALF) * D_DIM;
}

// 256 blocks x 32 rows: sq + colpart (coalesced row reads), then
// fragment-major fp16 convert with COALESCED 16B stores.
__global__ __launch_bounds__(256) void prep_kernel(const float* __restrict__ src,
                                                   const float* __restrict__ tgt,
                                                   _Float16* __restrict__ a16f,
                                                   float* __restrict__ sq,
                                                   float* __restrict__ colpart) {
    int tid = threadIdx.x, w = tid >> 6, lane = tid & 63;
    int r0 = blockIdx.x * 32;

    // row sq: each wave handles 8 rows, lane = float4 slot
    #pragma unroll
    for (int i = 0; i < 8; ++i) {
        int row = r0 + w * 8 + i;
        const float* rp = row_base(src, tgt, row);
        float4 v = ((const float4*)rp)[lane];
        float s = v.x*v.x + v.y*v.y + v.z*v.z + v.w*v.w;
        #pragma unroll
        for (int off = 32; off; off >>= 1) s += __shfl_down(s, off, 64);
        if (lane == 0) sq[row] = s;
    }

    // column partials: thread t sums column t over this block's 32 rows
    float c = 0.f;
    for (int r = r0; r < r0 + 32; ++r)
        c += row_base(src, tgt, r)[tid];
    colpart[blockIdx.x * D_DIM + tid] = c;

    // fragment-major convert: wave-task = (kb, 64-row group).
    // 32 kb x 128 groups = 4096 tasks / 1024 waves = 4 per wave.
    // lane loads 8 floats from its row (strided), stores 16B coalesced.
    int wg = blockIdx.x * 4 + w;                   // 0..1023
    #pragma unroll
    for (int i = 0; i < 4; ++i) {
        int t  = wg * 4 + i;                       // 0..4095
        int kb = t >> 7, rg = t & 127;
        int row = rg * 64 + lane;
        const float* rp = row_base(src, tgt, row) + kb * 8;
        float4 v0 = ((const float4*)rp)[0];
        float4 v1 = ((const float4*)rp)[1];
        _Float16 h[8] = {(_Float16)v0.x, (_Float16)v0.y, (_Float16)v0.z, (_Float16)v0.w,
                         (_Float16)v1.x, (_Float16)v1.y, (_Float16)v1.z, (_Float16)v1.w};
        *(f16x8*)(a16f + ((size_t)kb * N_TOTAL + row) * 8) = *(f16x8*)h;
    }
}

__global__ __launch_bounds__(256) void bw_kernel(const float* __restrict__ sq,
                                                 const float* __restrict__ colpart,
                                                 float* __restrict__ negc,
                                                 double* __restrict__ accum) {
    __shared__ double red[256];
    int t = threadIdx.x;
    double s = 0.0;
    for (int i = t; i < N_TOTAL; i += 256) s += (double)sq[i];
    red[t] = s;
    __syncthreads();
    for (int off = 128; off; off >>= 1) {
        if (t < off) red[t] += red[t + off];
        __syncthreads();
    }
    double sumsq = red[0];
    __syncthreads();
    float c = 0.f;
    for (int k = 0; k < 256; ++k) c += colpart[k * D_DIM + t];
    red[t] = (double)c * (double)c;
    __syncthreads();
    for (int off = 128; off; off >>= 1) {
        if (t < off) red[t] += red[t + off];
        __syncthreads();
    }
    if (t == 0) {
        double S1 = 2.0 * (double)N_TOTAL * sumsq - 2.0 * red[0];
        double nn = (double)N_TOTAL * (double)N_TOTAL - (double)N_TOTAL;
        double bw = S1 / nn / 4.0;    // KERNEL_MUL^(KERNEL_NUM//2) = 4
        negc[0] = (float)(-1.4426950408889634 / (16.0 * bw));
        accum[0] = 0.0;
    }
}

__global__ __launch_bounds__(256, 4) void mmd_main(const _Float16* __restrict__ a16f,
                                                   const float* __restrict__ sq,
                                                   const float* __restrict__ negc,
                                                   double* __restrict__ accum) {
    __shared__ float wsum[4];

    // T1: XCD swizzle (2080 % 8 == 0 -> bijective), then triangle decode (jt >= it)
    int b  = blockIdx.x;
    int bs = (b & 7) * (NTRI / 8) + (b >> 3);
    int it = 0, cum = 0;
    while (cum + (NTILE - it) <= bs) { cum += NTILE - it; ++it; }
    int jt = it + (bs - cum);

    int tid = threadIdx.x, lane = tid & 63, wid = tid >> 6;
    int wrow = wid >> 1, wcol = wid & 1;      // 2x2 wave grid; per-wave 64x64
    int rowA = it * TILE, rowB = jt * TILE;
    int c32 = lane & 31, khalf = lane >> 5;

    // fragment-major: element (row, k) at a16f[((k>>3)*8192 + row)*8 + (k&7)].
    // lane fragment (kap, khalf): kb = kap*2 + khalf, 16B at ((kb*8192+row)*8).
    const _Float16* PA = a16f + (size_t)khalf * (N_TOTAL * 8)
                              + (size_t)(rowA + wrow * 64 + c32) * 8;
    const _Float16* PB = a16f + (size_t)khalf * (N_TOTAL * 8)
                              + (size_t)(rowB + wcol * 64 + c32) * 8;

    f32x16 acc[2][2] = {};

    #pragma unroll 4
    for (int kap = 0; kap < 16; ++kap) {      // K = 256 in steps of 16
        size_t ko = (size_t)kap * (N_TOTAL * 16);   // 2 k-blocks per step
        f16x8 af[2], bf[2];
        af[0] = *(const f16x8*)(PA + ko);
        af[1] = *(const f16x8*)(PA + ko + 32 * 8);
        bf[0] = *(const f16x8*)(PB + ko);
        bf[1] = *(const f16x8*)(PB + ko + 32 * 8);
        __builtin_amdgcn_s_setprio(1);        // T5: free-running waves regime
        #pragma unroll
        for (int mt = 0; mt < 2; ++mt)
            #pragma unroll
            for (int nt = 0; nt < 2; ++nt)
                acc[mt][nt] = __builtin_amdgcn_mfma_f32_32x32x16_f16(af[mt], bf[nt], acc[mt][nt], 0, 0, 0);
        __builtin_amdgcn_s_setprio(0);
    }

    // fused epilogue: d2 -> 5-kernel sum. C/D: col=lane&31, row=(reg&3)+8*(reg>>2)+4*khalf
    float nc = *negc;
    float sjn[2];
    #pragma unroll
    for (int nt = 0; nt < 2; ++nt)
        sjn[nt] = sq[rowB + wcol * 64 + nt * 32 + c32];
    float tsum = 0.f;
    #pragma unroll
    for (int mt = 0; mt < 2; ++mt) {
        #pragma unroll
        for (int reg = 0; reg < 16; ++reg) {
            int i = rowA + wrow * 64 + mt * 32 + (reg & 3) + 8 * (reg >> 2) + 4 * khalf;
            float si = sq[i];
            #pragma unroll
            for (int nt = 0; nt < 2; ++nt) {
                float d2 = fmaxf(si + sjn[nt] - 2.0f * acc[mt][nt][reg], 0.f);
                float u  = exp2f(nc * d2);
                float u2 = u * u, u4 = u2 * u2, u8 = u4 * u4;
                tsum += u + u2 + u4 + u8 + u8 * u8;
            }
        }
    }
    float scale = (((it < 32) == (jt < 32)) ? 1.f : -1.f) * ((it == jt) ? 1.f : 2.f);
    tsum *= scale;

    #pragma unroll
    for (int off = 32; off; off >>= 1) tsum += __shfl_down(tsum, off, 64);
    if (lane == 0) wsum[wid] = tsum;
    __syncthreads();
    if (tid == 0) {
        float t = wsum[0] + wsum[1] + wsum[2] + wsum[3];
        atomicAdd(accum, (double)t);
    }
}

__global__ void finalize_kernel(const double* __restrict__ accum, float* __restrict__ out) {
    out[0] = (float)(accum[0] / ((double)B_HALF * (double)B_HALF));
}

extern "C" void kernel_launch(void* const* d_in, const int* in_sizes, int n_in,
                              void* d_out, int out_size, void* d_ws, size_t ws_size,
                              hipStream_t stream) {
    const float* src = (const float*)d_in[0];
    const float* tgt = (const float*)d_in[1];
    float* out = (float*)d_out;

    char* ws = (char*)d_ws;
    float*  sq      = (float*)ws;                         // 32 KB
    float*  colpart = (float*)(ws + 32768);               // 256 x 256 f32 = 256 KB
    float*  negc    = (float*)(ws + 294912);
    double* accum   = (double*)(ws + 294920);
    _Float16* a16f  = (_Float16*)(ws + 327680);           // 4 MB plane (fragment-major)

    prep_kernel<<<256, 256, 0, stream>>>(src, tgt, a16f, sq, colpart);
    bw_kernel<<<1, 256, 0, stream>>>(sq, colpart, negc, accum);
    mmd_main<<<NTRI, 256, 0, stream>>>(a16f, sq, negc, accum);
    finalize_kernel<<<1, 1, 0, stream>>>(accum, out);
}